// Round 23
// baseline (60.968 us; speedup 1.0000x reference)
//
#include <hip/hip_runtime.h>

#define BAND 8
#define NITER (BAND + 4)
#define NSLOT 1024
#define CHSPLIT 38   // streams: ch and ch+38 (76 channels total)

typedef float v2f __attribute__((ext_vector_type(2)));

__device__ __forceinline__ v2f fma2k(float k, v2f a, v2f b) {
    v2f vk = {k, k};
    return __builtin_elementwise_fma(vk, a, b);   // -> v_pk_fma_f32
}

#define LOG2E 0.14426950408889635f   // 0.1 * log2(e)
#define LN2   0.6931471805599453f

__global__ __launch_bounds__(256) void nms_loss_kernel(
    const float* __restrict__ tl, const float* __restrict__ pl,
    double* __restrict__ acc_d, float* __restrict__ acc_f,
    int H, int W)
{
    const int y0  = blockIdx.x * BAND;
    const int ch  = blockIdx.y;                 // stream 0: ch, stream 1: ch+CHSPLIT
    const size_t hw = (size_t)H * W;
    const float* tcs[2] = {tl + (size_t)ch * hw, tl + (size_t)(ch + CHSPLIT) * hw};
    const float* pcs[2] = {pl + (size_t)ch * hw, pl + (size_t)(ch + CHSPLIT) * hw};
    const int tid  = threadIdx.x;
    const int lane = tid & 63;
    const int c0 = tid << 1;                    // 2 output columns per thread
    const int oa = min(max(c0 - 2, 0), W - 2);  // clamped float2 bases
    const int oc = min(c0 + 2, W - 2);
    const bool eL = (c0 == 0), eR = (c0 == W - 2);
    const float eL2 = eL ? 2.f : 0.f, eR2 = eR ? 2.f : 0.f;

    // dual-stream rings: P (5 rows, j-pair packed), e (3 rows), lp, mask
    v2f P1v[2][5], P2v[2][5], P3v[2][5];
    float eh[2][3][4];
    v2f tch[2][3], lpv[2][3];
    float t6[2][6], p6[2][6];

    // t row y0-2+I (clamp), p row y0-3+I (reflect), both streams; ghost swaps
    #define LOADROW(I) {                                                            \
        int tr_ = y0 - 2 + (I); tr_ = min(max(tr_, 0), H - 1);                       \
        int pr_ = y0 - 3 + (I); pr_ = pr_ < 0 ? -pr_ : (pr_ >= H ? 2*H-2-pr_ : pr_); \
        _Pragma("unroll")                                                            \
        for (int s_ = 0; s_ < 2; ++s_) {                                             \
            const float* tb_ = tcs[s_] + (size_t)tr_ * W;                            \
            const float* pb_ = pcs[s_] + (size_t)pr_ * W;                            \
            float2 a_ = *(const float2*)(tb_ + oa), b_ = *(const float2*)(tb_ + c0), \
                   c_ = *(const float2*)(tb_ + oc);                                  \
            t6[s_][0]=a_.x; t6[s_][1]=a_.y; t6[s_][2]=b_.x;                          \
            t6[s_][3]=b_.y; t6[s_][4]=c_.x; t6[s_][5]=c_.y;                          \
            a_ = *(const float2*)(pb_ + oa); b_ = *(const float2*)(pb_ + c0);        \
            c_ = *(const float2*)(pb_ + oc);                                         \
            p6[s_][0]=a_.x; p6[s_][1]=a_.y; p6[s_][2]=b_.x;                          \
            p6[s_][3]=b_.y; p6[s_][4]=c_.x; p6[s_][5]=c_.y;                          \
            float g0_ = t6[s_][0];                                                   \
            t6[s_][0] = eL ? t6[s_][1] : t6[s_][0];                                  \
            t6[s_][1] = eL ? g0_      : t6[s_][1];                                   \
            float g4_ = t6[s_][4];                                                   \
            t6[s_][4] = eR ? t6[s_][5] : t6[s_][4];                                  \
            t6[s_][5] = eR ? g4_      : t6[s_][5];                                   \
        } }

    // consume pending row: packed H-taps + exp2-folded e (both streams)
    #define CONSUME(SP, SE) {                                                        \
        _Pragma("unroll")                                                            \
        for (int s_ = 0; s_ < 2; ++s_) {                                             \
            v2f Av = {t6[s_][0], t6[s_][1]}, Bv = {t6[s_][1], t6[s_][2]};            \
            v2f Cv = {t6[s_][2], t6[s_][3]}, Dv = {t6[s_][3], t6[s_][4]};            \
            v2f Ev = {t6[s_][4], t6[s_][5]};                                         \
            v2f s04 = Av + Ev, s13 = Bv + Dv;                                        \
            P1v[s_][SP] = fma2k(-2.f, Cv, s04);                                      \
            P3v[s_][SP] = fma2k(6.f, Cv, fma2k(4.f, s13, s04));                      \
            P2v[s_][SP] = fma2k(2.f, Dv - Bv, Ev - Av);                              \
            P1v[s_][SP].x = fmaf(eL2, t6[s_][2] - t6[s_][3], P1v[s_][SP].x);         \
            P1v[s_][SP].y = fmaf(eR2, t6[s_][3] - t6[s_][2], P1v[s_][SP].y);         \
            tch[s_][SE] = Cv;                                                        \
            float a0_ = LOG2E * p6[s_][1], a1_ = LOG2E * p6[s_][2];                  \
            float a2_ = LOG2E * p6[s_][3], a3_ = LOG2E * p6[s_][4];                  \
            eh[s_][SE][0] = exp2f(a0_);                                              \
            eh[s_][SE][1] = exp2f(a1_);                                              \
            eh[s_][SE][2] = exp2f(a2_);                                              \
            eh[s_][SE][3] = exp2f(a3_);                                              \
            lpv[s_][SE] = (v2f){a1_, a2_};                                           \
        } }

    // output row y = y0 + I - 4 (packed V-pass + validated y-edge fixups)
    #define OUTPUT(I) if ((I) >= 4) {                                                \
        const int y = y0 + (I) - 4;                                                  \
        const int s0=((I)-4)%5, s1=((I)-3)%5, s2=((I)-2)%5, s3=((I)-1)%5, s4=(I)%5;  \
        const int et=((I)-2)%3, em=((I)-1)%3, ebq=(I)%3;                             \
        const bool ytop = (y == 0), ybot = (y == H - 1);                             \
        _Pragma("unroll")                                                            \
        for (int s_ = 0; s_ < 2; ++s_) {                                             \
            v2f a04 = P1v[s_][s0] + P1v[s_][s4], a13 = P1v[s_][s1] + P1v[s_][s3];    \
            v2f xx = fma2k(6.f, P1v[s_][s2], fma2k(4.f, a13, a04));                  \
            v2f xy = fma2k(2.f, P2v[s_][s3] - P2v[s_][s1], P2v[s_][s4] - P2v[s_][s0]);\
            v2f yy = fma2k(-2.f, P3v[s_][s2], P3v[s_][s0] + P3v[s_][s4]);            \
            if (ytop) {                                                              \
                xx += P1v[s_][s3] - P1v[s_][s2];                                     \
                xy += P2v[s_][s3] - P2v[s_][s2];                                     \
                yy += P3v[s_][s2] - P3v[s_][s3];                                     \
            } else if (ybot) {                                                       \
                xx += P1v[s_][s1] - P1v[s_][s2];                                     \
                xy += P2v[s_][s2] - P2v[s_][s1];                                     \
                yy += P3v[s_][s2] - P3v[s_][s1];                                     \
            }                                                                        \
            v2f den = xx + 6.4e-6f;                                                  \
            v2f sa  = 6.4e-6f - xy;                                                  \
            _Pragma("unroll")                                                        \
            for (int j = 0; j < 2; ++j) {                                            \
                float tcv = j ? tch[s_][et].y : tch[s_][et].x;                       \
                if (tcv > 0.f) {                                                     \
                    float dj = j ? den.y : den.x;                                    \
                    float sj = j ? sa.y  : sa.x;                                     \
                    float yj = j ? yy.y  : yy.x;                                     \
                    float ax = fabsf(dj), ay = fabsf(yj);                            \
                    bool isH = ay < 0.41421356f * ax;                                \
                    bool isV = ay >= 2.41421356f * ax;                               \
                    bool qp  = ((yj * sj) * dj) > 0.f;                               \
                    float ec = eh[s_][em][j + 1];                                    \
                    float n1 = isH ? eh[s_][em][j + 2] : (isV ? eh[s_][ebq][j + 1]   \
                                    : (qp ? eh[s_][ebq][j] : eh[s_][ebq][j + 2]));   \
                    float n2 = isH ? eh[s_][em][j]     : (isV ? eh[s_][et][j + 1]    \
                                    : (qp ? eh[s_][et][j + 2] : eh[s_][et][j]));     \
                    float lp = j ? lpv[s_][em].y : lpv[s_][em].x;                    \
                    partial += lp - __log2f(ec + n1 + n2 + 1e-7f);                   \
                }                                                                    \
            }                                                                        \
        } }

    LOADROW(0)

    float partial = 0.f;   // log2 units; scaled by ln2 once per wave

    #pragma unroll
    for (int i = 0; i < NITER; ++i) {
        CONSUME(i % 5, i % 3)
        if (i + 1 < NITER) LOADROW(i + 1)
        OUTPUT(i)
    }

    // ---- wave reduction + spread atomics (no barriers anywhere) ----
    for (int off = 32; off > 0; off >>= 1)
        partial += __shfl_down(partial, off, 64);
    if (lane == 0) {
        int fid = (blockIdx.y * gridDim.x + blockIdx.x) * 4 + (tid >> 6);
        if (acc_d) atomicAdd(&acc_d[fid & (NSLOT - 1)], (double)(partial * LN2));
        else       atomicAdd(acc_f, partial * LN2);
    }
}

__global__ void finalize_kernel(const double* acc_d, float* out,
                                int use_double, float inv_b)
{
    if (use_double) {
        int l = threadIdx.x;
        double s = 0.0;
        for (int i = l; i < NSLOT; i += 64) s += acc_d[i];
        for (int off = 32; off > 0; off >>= 1) s += __shfl_down(s, off, 64);
        if (l == 0) out[0] = (float)(-s * (double)inv_b);
    } else {
        if (threadIdx.x == 0) out[0] = -out[0] * inv_b;
    }
}

extern "C" void kernel_launch(void* const* d_in, const int* in_sizes, int n_in,
                              void* d_out, int out_size, void* d_ws, size_t ws_size,
                              hipStream_t stream)
{
    const float* tl = (const float*)d_in[0];
    const float* pl = (const float*)d_in[1];
    float* out = (float*)d_out;

    const int H = 512, W = 512, B = 4;

    double* acc_d = nullptr;
    float* acc_f = nullptr;
    int use_double = 0;
    if (ws_size >= NSLOT * sizeof(double)) {
        acc_d = (double*)d_ws;
        use_double = 1;
        hipMemsetAsync(acc_d, 0, NSLOT * sizeof(double), stream);
    } else {
        acc_f = out;
        hipMemsetAsync(out, 0, sizeof(float), stream);
    }

    // 64 bands x 38 channel-pairs = 2432 blocks (9728 waves), 2 channels/thread
    dim3 grid(H / BAND, CHSPLIT, 1);
    nms_loss_kernel<<<grid, 256, 0, stream>>>(tl, pl, acc_d, acc_f, H, W);
    finalize_kernel<<<1, 64, 0, stream>>>(acc_d, out, use_double, 1.0f / (float)B);
}

// Round 24
// 55.057 us; speedup vs baseline: 1.1074x; 1.1074x over previous
//
#include <hip/hip_runtime.h>

#define BAND 8
#define NITER (BAND + 4)
#define NSLOT 1024

typedef float v2f __attribute__((ext_vector_type(2)));

__device__ __forceinline__ v2f fma2k(float k, v2f a, v2f b) {
    v2f vk = {k, k};
    return __builtin_elementwise_fma(vk, a, b);   // -> v_pk_fma_f32
}

__global__ __launch_bounds__(256) void nms_loss_kernel(
    const float* __restrict__ tl, const float* __restrict__ pl,
    double* __restrict__ acc_d, float* __restrict__ acc_f,
    int H, int W)
{
    const int y0  = blockIdx.x * BAND;
    const int ch  = blockIdx.y;
    const float* tc = tl + (size_t)ch * H * W;
    const float* pc = pl + (size_t)ch * H * W;
    const int tid  = threadIdx.x;
    const int lane = tid & 63;
    const int c0 = tid << 1;                    // 2 output columns per thread
    const int oa = min(max(c0 - 2, 0), W - 2);  // clamped float2 bases
    const int oc = min(c0 + 2, W - 2);
    const bool eL = (c0 == 0), eR = (c0 == W - 2);
    const float eL2 = eL ? 2.f : 0.f, eR2 = eR ? 2.f : 0.f;

    // rings: P (5 rows, v2f = j-pair packed), e (3 rows), mask (3 rows)
    v2f P1v[5], P2v[5], P3v[5];
    float eh[3][4];
    v2f tch[3];
    float t6[6], p6[6];

    // t row y0-2+I (clamp), p row y0-3+I (reflect); t-edge ghosts via swap
    // (R18-validated); p-edge reflect ghosts automatic from clamped base.
    #define LOADROW(I) {                                                            \
        int tr_ = y0 - 2 + (I); tr_ = min(max(tr_, 0), H - 1);                       \
        int pr_ = y0 - 3 + (I); pr_ = pr_ < 0 ? -pr_ : (pr_ >= H ? 2*H-2-pr_ : pr_); \
        const float* tb_ = tc + (size_t)tr_ * W;                                     \
        const float* pb_ = pc + (size_t)pr_ * W;                                     \
        float2 a_ = *(const float2*)(tb_ + oa), b_ = *(const float2*)(tb_ + c0),     \
               c_ = *(const float2*)(tb_ + oc);                                      \
        t6[0]=a_.x; t6[1]=a_.y; t6[2]=b_.x; t6[3]=b_.y; t6[4]=c_.x; t6[5]=c_.y;      \
        a_ = *(const float2*)(pb_ + oa); b_ = *(const float2*)(pb_ + c0);            \
        c_ = *(const float2*)(pb_ + oc);                                             \
        p6[0]=a_.x; p6[1]=a_.y; p6[2]=b_.x; p6[3]=b_.y; p6[4]=c_.x; p6[5]=c_.y;      \
        float g0_ = t6[0];                                                           \
        t6[0] = eL ? t6[1] : t6[0];                                                  \
        t6[1] = eL ? g0_   : t6[1];                                                  \
        float g4_ = t6[4];                                                           \
        t6[4] = eR ? t6[5] : t6[4];                                                  \
        t6[5] = eR ? g4_   : t6[5]; }

    // consume pending row into P slot SP (packed), eh/tch slot SE
    #define CONSUME(SP, SE) {                                                        \
        v2f Av = {t6[0], t6[1]}, Bv = {t6[1], t6[2]}, Cv = {t6[2], t6[3]};           \
        v2f Dv = {t6[3], t6[4]}, Ev = {t6[4], t6[5]};                                \
        v2f s04 = Av + Ev, s13 = Bv + Dv;                                            \
        P1v[SP] = fma2k(-2.f, Cv, s04);                       /* hdd */              \
        P3v[SP] = fma2k(6.f, Cv, fma2k(4.f, s13, s04));       /* hss */              \
        P2v[SP] = fma2k(2.f, Dv - Bv, Ev - Av);               /* hds */              \
        P1v[SP].x = fmaf(eL2, t6[2] - t6[3], P1v[SP].x);      /* edge residuals */   \
        P1v[SP].y = fmaf(eR2, t6[3] - t6[2], P1v[SP].y);                             \
        tch[SE] = Cv;                                                                \
        eh[SE][0] = __expf(0.1f * p6[1]);                                            \
        eh[SE][1] = __expf(0.1f * p6[2]);                                            \
        eh[SE][2] = __expf(0.1f * p6[3]);                                            \
        eh[SE][3] = __expf(0.1f * p6[4]); }

    // output row y = y0 + I - 4 (packed V-pass + R18-validated y-edge fixups)
    #define OUTPUT(I) if ((I) >= 4) {                                                \
        const int y = y0 + (I) - 4;                                                  \
        const int s0=((I)-4)%5, s1=((I)-3)%5, s2=((I)-2)%5, s3=((I)-1)%5, s4=(I)%5;  \
        const int et=((I)-2)%3, em=((I)-1)%3, ebq=(I)%3;                             \
        const bool ytop = (y == 0), ybot = (y == H - 1);                             \
        v2f a04 = P1v[s0] + P1v[s4], a13 = P1v[s1] + P1v[s3];                        \
        v2f xx = fma2k(6.f, P1v[s2], fma2k(4.f, a13, a04));                          \
        v2f xy = fma2k(2.f, P2v[s3] - P2v[s1], P2v[s4] - P2v[s0]);                   \
        v2f yy = fma2k(-2.f, P3v[s2], P3v[s0] + P3v[s4]);                            \
        if (ytop) {                                                                  \
            xx += P1v[s3] - P1v[s2];                                                 \
            xy += P2v[s3] - P2v[s2];                                                 \
            yy += P3v[s2] - P3v[s3];                                                 \
        } else if (ybot) {                                                           \
            xx += P1v[s1] - P1v[s2];                                                 \
            xy += P2v[s2] - P2v[s1];                                                 \
            yy += P3v[s2] - P3v[s1];                                                 \
        }                                                                            \
        v2f den = xx + 6.4e-6f;                                                      \
        v2f sa  = 6.4e-6f - xy;                                                      \
        _Pragma("unroll")                                                            \
        for (int j = 0; j < 2; ++j) {                                                \
            float tcv = j ? tch[et].y : tch[et].x;                                   \
            if (tcv > 0.f) {                                                         \
                float dj = j ? den.y : den.x;                                        \
                float sj = j ? sa.y  : sa.x;                                         \
                float yj = j ? yy.y  : yy.x;                                         \
                float ax = fabsf(dj), ay = fabsf(yj);                                \
                bool isH = ay < 0.41421356f * ax;                                    \
                bool isV = ay >= 2.41421356f * ax;                                   \
                bool qp  = ((yj * sj) * dj) > 0.f;                                   \
                float ec = eh[em][j + 1];                                            \
                float n1 = isH ? eh[em][j + 2] : (isV ? eh[ebq][j + 1]               \
                                : (qp ? eh[ebq][j] : eh[ebq][j + 2]));               \
                float n2 = isH ? eh[em][j]     : (isV ? eh[et][j + 1]                \
                                : (qp ? eh[et][j + 2] : eh[et][j]));                 \
                partial += __logf(__fdividef(ec, ec + n1 + n2 + 1e-7f));             \
            }                                                                        \
        } }

    LOADROW(0)

    float partial = 0.f;

    #pragma unroll
    for (int i = 0; i < NITER; ++i) {
        CONSUME(i % 5, i % 3)
        if (i + 1 < NITER) LOADROW(i + 1)
        OUTPUT(i)
    }

    // ---- wave reduction + spread atomics (no barriers anywhere) ----
    for (int off = 32; off > 0; off >>= 1)
        partial += __shfl_down(partial, off, 64);
    if (lane == 0) {
        int fid = (blockIdx.y * gridDim.x + blockIdx.x) * 4 + (tid >> 6);
        if (acc_d) atomicAdd(&acc_d[fid & (NSLOT - 1)], (double)partial);
        else       atomicAdd(acc_f, partial);
    }
}

__global__ void finalize_kernel(const double* acc_d, float* out,
                                int use_double, float inv_b)
{
    if (use_double) {
        int l = threadIdx.x;
        double s = 0.0;
        for (int i = l; i < NSLOT; i += 64) s += acc_d[i];
        for (int off = 32; off > 0; off >>= 1) s += __shfl_down(s, off, 64);
        if (l == 0) out[0] = (float)(-s * (double)inv_b);
    } else {
        if (threadIdx.x == 0) out[0] = -out[0] * inv_b;
    }
}

extern "C" void kernel_launch(void* const* d_in, const int* in_sizes, int n_in,
                              void* d_out, int out_size, void* d_ws, size_t ws_size,
                              hipStream_t stream)
{
    const float* tl = (const float*)d_in[0];
    const float* pl = (const float*)d_in[1];
    float* out = (float*)d_out;

    const int H = 512, W = 512, B = 4;

    double* acc_d = nullptr;
    float* acc_f = nullptr;
    int use_double = 0;
    if (ws_size >= NSLOT * sizeof(double)) {
        acc_d = (double*)d_ws;
        use_double = 1;
        hipMemsetAsync(acc_d, 0, NSLOT * sizeof(double), stream);
    } else {
        acc_f = out;
        hipMemsetAsync(out, 0, sizeof(float), stream);
    }

    dim3 grid(H / BAND, 76, 1);   // 64 bands x 76 channels = 4864 blocks (19456 waves)
    nms_loss_kernel<<<grid, 256, 0, stream>>>(tl, pl, acc_d, acc_f, H, W);
    finalize_kernel<<<1, 64, 0, stream>>>(acc_d, out, use_double, 1.0f / (float)B);
}